// Round 5
// baseline (77.898 us; speedup 1.0000x reference)
//
#include <hip/hip_runtime.h>

#define P_NUM 40
#define N_VERT 128
#define H 256
#define W 256
#define BS 8
#define C_IN 64
#define PIX (H * W)
#define PIX4 (PIX / 4)

// clang native vector types (accepted by __builtin_nontemporal_store)
typedef float vf2 __attribute__((ext_vector_type(2)));
typedef float vf4 __attribute__((ext_vector_type(4)));

// Kernel A: even-odd point-in-polygon rasterization + direct scatter.
// One block per (polygon p, scanline y); 256 threads = one pixel column each.
// After computing the row parity, the block:
//  - nt-stores the row into out_mask[i,j,y,:] for every (i,j) channel whose
//    clipped index maps to p (faithful starts[i]=ct_num[i-1], jnp.clip),
//  - atomicOr's 0x3f800000 into max_mask rows where inside==1 (max of {0,1}
//    floats == bitwise OR; exact).
__global__ __launch_bounds__(256) void pnp_scatter_kernel(
    const float* __restrict__ contour, const int* __restrict__ ct_num,
    float* __restrict__ out_mask, float* __restrict__ max_mask, int C) {
    const int p = blockIdx.x;
    const int y = blockIdx.y;
    const int tid = threadIdx.x;

    __shared__ float sx[N_VERT];
    __shared__ float sy[N_VERT];
    __shared__ float xints[N_VERT];
    __shared__ int kcnt;

    if (tid < N_VERT) {
        const vf2 v = reinterpret_cast<const vf2*>(contour)[p * N_VERT + tid];
        sx[tid] = v.x;
        sy[tid] = v.y;
    }
    if (tid == 0) kcnt = 0;
    __syncthreads();

    const float py = (float)y;
    if (tid < N_VERT) {
        const float y1 = sy[tid];
        const int e2 = (tid + 1) & (N_VERT - 1);
        const float y2 = sy[e2];
        const bool crosses = (y1 > py) != (y2 > py);  // exactly as reference
        if (crosses) {
            const float x1 = sx[tid];
            const float x2 = sx[e2];
            const float denom = (y2 == y1) ? 1.0f : (y2 - y1);
            // mul -> div -> add: no FMA contraction; IEEE f32 == XLA bit-for-bit.
            const float xint = (x2 - x1) * (py - y1) / denom + x1;
            const int slot = atomicAdd(&kcnt, 1);
            xints[slot] = xint;
        }
    }
    __syncthreads();

    const int K = kcnt;
    const float px = (float)tid;
    int cnt = 0;
    for (int k = 0; k < K; ++k) {
        cnt += (px < xints[k]) ? 1 : 0;  // broadcast LDS read, conflict-free
    }
    const int v = cnt & 1;
    const float fv = (float)v;

    // Scatter this row into every (i,j) mask channel that references p.
    const int rowoff = y * W + tid;
    int prev = 0;
    for (int i = 0; i < BS; ++i) {
        const int cn = ct_num[i];      // uniform scalar load, cached
        const int start = prev;        // faithful: starts[i] = ct_num[i-1]
        prev = cn;
        bool used = false;
        for (int j = 0; j < cn; ++j) {
            const int pc = min(max(start + j, 0), P_NUM - 1);  // jnp.clip
            if (pc == p) {
                used = true;
                __builtin_nontemporal_store(
                    fv, out_mask + (size_t)(i * C + j) * PIX + rowoff);
            }
        }
        if (used && v) {
            atomicOr(reinterpret_cast<unsigned int*>(max_mask) + i * PIX + rowoff,
                     0x3f800000u);
        }
    }
}

// Kernel B: block-specialized tail.
//  blocks [0, FUSE_BLOCKS): elementwise relu(mx*f + f), full-occupancy stream.
//  blocks [FUSE_BLOCKS, ..): zero-fill the invalid (j >= ct_num[i]) mask planes.
__global__ __launch_bounds__(256) void fuse_zero_kernel(
    const float* __restrict__ feat, const float* __restrict__ max_mask,
    const int* __restrict__ ct_num, float* __restrict__ out_mask,
    float* __restrict__ out_cnn, int C) {
    const int FUSE_BLOCKS = BS * C_IN * PIX4 / 256;  // 32768
    if ((int)blockIdx.x < FUSE_BLOCKS) {
        const int gid = blockIdx.x * 256 + threadIdx.x;  // BS*C_IN*PIX4
        const int ic = gid / PIX4;   // i*C_IN + c
        const int q = gid - ic * PIX4;
        const int i = ic >> 6;       // /C_IN

        const vf4 f = reinterpret_cast<const vf4*>(feat)[(size_t)ic * PIX4 + q];
        const vf4 mm = reinterpret_cast<const vf4*>(max_mask)[i * PIX4 + q];
        vf4 r;
        // m in {0,1} exactly -> m*f+f == f or 2f exactly, FMA-insensitive.
        r.x = fmaxf(mm.x * f.x + f.x, 0.0f);
        r.y = fmaxf(mm.y * f.y + f.y, 0.0f);
        r.z = fmaxf(mm.z * f.z + f.z, 0.0f);
        r.w = fmaxf(mm.w * f.w + f.w, 0.0f);
        __builtin_nontemporal_store(
            r, reinterpret_cast<vf4*>(out_cnn) + (size_t)ic * PIX4 + q);
    } else {
        const int gid = (blockIdx.x - FUSE_BLOCKS) * 256 + threadIdx.x;  // BS*C*PIX4
        const int ij = gid / PIX4;
        const int q = gid - ij * PIX4;
        const int i = ij / C;
        const int j = ij - i * C;
        if (j >= ct_num[i]) {  // valid planes were written by pnp_scatter
            vf4 z = {0.f, 0.f, 0.f, 0.f};
            __builtin_nontemporal_store(
                z, reinterpret_cast<vf4*>(out_mask) + (size_t)ij * PIX4 + q);
        }
    }
}

extern "C" void kernel_launch(void* const* d_in, const int* in_sizes, int n_in,
                              void* d_out, int out_size, void* d_ws, size_t ws_size,
                              hipStream_t stream) {
    const float* contour = (const float*)d_in[0];  // [P, N, 2] f32
    const float* feat = (const float*)d_in[1];     // [BS, C_IN, H, W] f32
    const int* ct_num = (const int*)d_in[2];       // [BS] i32

    float* out = (float*)d_out;
    const int cnn_elems = BS * C_IN * PIX;
    const int C = (out_size - cnn_elems) / (BS * PIX);  // = max(ct_num)

    float* max_mask = (float*)d_ws;                // [BS, H, W] = 2 MB
    float* out_mask = out;
    float* out_cnn = out + (size_t)BS * C * PIX;

    // Zero-init max_mask (atomicOr accumulator). Async memset is capturable.
    hipMemsetAsync(max_mask, 0, (size_t)BS * PIX * sizeof(float), stream);

    hipLaunchKernelGGL(pnp_scatter_kernel, dim3(P_NUM, H), dim3(256), 0, stream,
                       contour, ct_num, out_mask, max_mask, C);

    const int fuse_blocks = BS * C_IN * PIX4 / 256;  // 32768
    const int zero_blocks = (BS * C * PIX4 + 255) / 256;
    hipLaunchKernelGGL(fuse_zero_kernel, dim3(fuse_blocks + zero_blocks),
                       dim3(256), 0, stream, feat, max_mask, ct_num, out_mask,
                       out_cnn, C);
}

// Round 6
// 65.957 us; speedup vs baseline: 1.1810x; 1.1810x over previous
//
#include <hip/hip_runtime.h>

#define P_NUM 40
#define N_VERT 128
#define H 256
#define W 256
#define BS 8
#define C_IN 64
#define PIX (H * W)
#define PIX4 (PIX / 4)
#define CSPLIT 4               // c-quarters per pixel chunk
#define CPS (C_IN / CSPLIT)    // 16 channels per split

// clang native vector types (accepted by __builtin_nontemporal_store)
typedef float vf2 __attribute__((ext_vector_type(2)));
typedef float vf4 __attribute__((ext_vector_type(4)));

// Kernel A: even-odd point-in-polygon rasterization.
// One block per (polygon p, scanline y); 256 threads = one pixel column each.
__global__ __launch_bounds__(256) void pnp_mask_kernel(
    const float* __restrict__ contour, float* __restrict__ maskws) {
    const int p = blockIdx.x;
    const int y = blockIdx.y;
    const int tid = threadIdx.x;

    __shared__ float sx[N_VERT];
    __shared__ float sy[N_VERT];
    __shared__ float xints[N_VERT];
    __shared__ int kcnt;

    if (tid < N_VERT) {
        const vf2 v = reinterpret_cast<const vf2*>(contour)[p * N_VERT + tid];
        sx[tid] = v.x;
        sy[tid] = v.y;
    }
    if (tid == 0) kcnt = 0;
    __syncthreads();

    const float py = (float)y;
    if (tid < N_VERT) {
        const float y1 = sy[tid];
        const int e2 = (tid + 1) & (N_VERT - 1);
        const float y2 = sy[e2];
        const bool crosses = (y1 > py) != (y2 > py);  // exactly as reference
        if (crosses) {
            const float x1 = sx[tid];
            const float x2 = sx[e2];
            const float denom = (y2 == y1) ? 1.0f : (y2 - y1);
            // mul -> div -> add: no FMA contraction; IEEE f32 == XLA bit-for-bit.
            const float xint = (x2 - x1) * (py - y1) / denom + x1;
            const int slot = atomicAdd(&kcnt, 1);
            xints[slot] = xint;
        }
    }
    __syncthreads();

    const int K = kcnt;
    const float px = (float)tid;
    int cnt = 0;
    for (int k = 0; k < K; ++k) {
        cnt += (px < xints[k]) ? 1 : 0;  // broadcast LDS read, conflict-free
    }
    maskws[(p * H + y) * W + tid] = (float)(cnt & 1);
}

// Mega-kernel: block = (image i, 1024-px chunk, c-quarter).
//  - every block: mx = running max over the cn gathered mask planes
//    (maskws is 10.5 MB, L2/L3-resident; max_mask lives in registers only)
//  - split 0 additionally nt-stores all C mask_batch planes (zeros for j>=cn)
//  - each split streams its 16 feature channels: relu(mx*f + f), nt-stored.
// 2048 blocks -> 8 blocks/CU, 32 waves/CU.
__global__ __launch_bounds__(256) void mega_kernel(
    const float* __restrict__ maskws, const float* __restrict__ feat,
    const int* __restrict__ ct_num, float* __restrict__ out_mask,
    float* __restrict__ out_cnn, int C) {
    const int bid = blockIdx.x;
    const int split = bid & (CSPLIT - 1);
    const int chunk = (bid >> 2) & 63;          // 64 chunks of 1024 px
    const int i = bid >> 8;                     // image
    const int qv = chunk * 256 + threadIdx.x;   // vf4 index within image

    const int cn = ct_num[i];
    const int start = (i == 0) ? 0 : ct_num[i - 1];  // faithful: NOT cumsum

    vf4 mx = {0.f, 0.f, 0.f, 0.f};
    if (split == 0) {
        // write all C planes; track max over the valid ones
        for (int j = 0; j < C; ++j) {
            vf4 m = {0.f, 0.f, 0.f, 0.f};
            if (j < cn) {
                const int p = min(max(start + j, 0), P_NUM - 1);  // jnp.clip
                m = reinterpret_cast<const vf4*>(maskws)[p * PIX4 + qv];
                mx.x = fmaxf(mx.x, m.x);
                mx.y = fmaxf(mx.y, m.y);
                mx.z = fmaxf(mx.z, m.z);
                mx.w = fmaxf(mx.w, m.w);
            }
            __builtin_nontemporal_store(
                m, reinterpret_cast<vf4*>(out_mask) + (size_t)(i * C + j) * PIX4 + qv);
        }
    } else {
        for (int j = 0; j < cn; ++j) {
            const int p = min(max(start + j, 0), P_NUM - 1);
            const vf4 m = reinterpret_cast<const vf4*>(maskws)[p * PIX4 + qv];
            mx.x = fmaxf(mx.x, m.x);
            mx.y = fmaxf(mx.y, m.y);
            mx.z = fmaxf(mx.z, m.z);
            mx.w = fmaxf(mx.w, m.w);
        }
    }

    const int cbase = split * CPS;
    for (int cc = 0; cc < CPS; ++cc) {
        const size_t idx = (size_t)(i * C_IN + cbase + cc) * PIX4 + qv;
        const vf4 f = reinterpret_cast<const vf4*>(feat)[idx];
        vf4 r;
        // m in {0,1} exactly -> m*f+f == f or 2f exactly, FMA-insensitive.
        r.x = fmaxf(mx.x * f.x + f.x, 0.0f);
        r.y = fmaxf(mx.y * f.y + f.y, 0.0f);
        r.z = fmaxf(mx.z * f.z + f.z, 0.0f);
        r.w = fmaxf(mx.w * f.w + f.w, 0.0f);
        __builtin_nontemporal_store(r, reinterpret_cast<vf4*>(out_cnn) + idx);
    }
}

extern "C" void kernel_launch(void* const* d_in, const int* in_sizes, int n_in,
                              void* d_out, int out_size, void* d_ws, size_t ws_size,
                              hipStream_t stream) {
    const float* contour = (const float*)d_in[0];  // [P, N, 2] f32
    const float* feat = (const float*)d_in[1];     // [BS, C_IN, H, W] f32
    const int* ct_num = (const int*)d_in[2];       // [BS] i32

    float* out = (float*)d_out;
    const int cnn_elems = BS * C_IN * PIX;
    const int C = (out_size - cnn_elems) / (BS * PIX);  // = max(ct_num)

    float* maskws = (float*)d_ws;                  // [P, H, W] = 10.5 MB
    float* out_mask = out;
    float* out_cnn = out + (size_t)BS * C * PIX;

    hipLaunchKernelGGL(pnp_mask_kernel, dim3(P_NUM, H), dim3(256), 0, stream,
                       contour, maskws);

    hipLaunchKernelGGL(mega_kernel, dim3(BS * 64 * CSPLIT), dim3(256), 0, stream,
                       maskws, feat, ct_num, out_mask, out_cnn, C);
}

// Round 8
// 57.233 us; speedup vs baseline: 1.3611x; 1.1524x over previous
//
#include <hip/hip_runtime.h>

#define P_NUM 40
#define N_VERT 128
#define H 256
#define W 256
#define BS 8
#define C_IN 64
#define PIX (H * W)
#define PIX4 (PIX / 4)         // 16384 vf4 per plane
#define CHUNKS 64              // 1024-px chunks per image
#define ASPLIT 8               // c-splits in fuse blocks
#define CPS (C_IN / ASPLIT)    // 8 channels per fuse block

typedef float vf2 __attribute__((ext_vector_type(2)));
typedef float vf4 __attribute__((ext_vector_type(4)));

// Kernel A: even-odd point-in-polygon rasterization -> BIT rows.
// One block per (polygon p, scanline y); 256 threads = one pixel column each.
// Row parity is emitted as 8 u32 words via __ballot (mask total = 320 KB).
__global__ __launch_bounds__(256) void pnp_bits_kernel(
    const float* __restrict__ contour, unsigned int* __restrict__ bitws) {
    const int p = blockIdx.x;
    const int y = blockIdx.y;
    const int tid = threadIdx.x;

    __shared__ float sx[N_VERT];
    __shared__ float sy[N_VERT];
    __shared__ float xints[N_VERT];
    __shared__ int kcnt;

    if (tid < N_VERT) {
        const vf2 v = reinterpret_cast<const vf2*>(contour)[p * N_VERT + tid];
        sx[tid] = v.x;
        sy[tid] = v.y;
    }
    if (tid == 0) kcnt = 0;
    __syncthreads();

    const float py = (float)y;
    if (tid < N_VERT) {
        const float y1 = sy[tid];
        const int e2 = (tid + 1) & (N_VERT - 1);
        const float y2 = sy[e2];
        const bool crosses = (y1 > py) != (y2 > py);  // exactly as reference
        if (crosses) {
            const float x1 = sx[tid];
            const float x2 = sx[e2];
            const float denom = (y2 == y1) ? 1.0f : (y2 - y1);
            // mul -> div -> add: no FMA contraction; IEEE f32 == XLA bit-for-bit.
            const float xint = (x2 - x1) * (py - y1) / denom + x1;
            const int slot = atomicAdd(&kcnt, 1);
            xints[slot] = xint;
        }
    }
    __syncthreads();

    const int K = kcnt;
    const float px = (float)tid;
    int cnt = 0;
    for (int k = 0; k < K; ++k) {
        cnt += (px < xints[k]) ? 1 : 0;  // broadcast LDS read, conflict-free
    }
    // parity bit -> ballot word; lane 0 of each wave stores 8 B.
    const unsigned long long b = __ballot(cnt & 1);
    if ((tid & 63) == 0) {
        // layout: bitws[(p*H + y)*8 + w], w = x/32 (little-endian u64 = w, w+1)
        *reinterpret_cast<unsigned long long*>(
            bitws + ((size_t)(p * H + y) << 3) + ((tid >> 6) << 1)) = b;
    }
}

__device__ __forceinline__ vf4 expand_bits(unsigned int word, int sh) {
    vf4 m;
    m.x = ((word >> (sh + 0)) & 1u) ? 1.0f : 0.0f;
    m.y = ((word >> (sh + 1)) & 1u) ? 1.0f : 0.0f;
    m.z = ((word >> (sh + 2)) & 1u) ? 1.0f : 0.0f;
    m.w = ((word >> (sh + 3)) & 1u) ? 1.0f : 0.0f;
    return m;
}

// Kernel B: block-specialized tail, one dispatch.
//  type A (first FUSE_BLOCKS): (image, 1024-px chunk, 8-channel split).
//    thread: OR the cn bit-words (u32 L1-broadcast loads) -> mx, then stream
//    8 feature channels: relu(mx*f + f), nt-stored. 4096 blocks.
//  type B (rest): mask_batch bit-expand. thread: 1 u32 load -> 4 floats,
//    nt-store; zeros for invalid j. 7680 blocks.
__global__ __launch_bounds__(256) void fuse_expand_kernel(
    const unsigned int* __restrict__ bitws, const float* __restrict__ feat,
    const int* __restrict__ ct_num, float* __restrict__ out_mask,
    float* __restrict__ out_cnn, int C) {
    const int FUSE_BLOCKS = BS * CHUNKS * ASPLIT;  // 4096
    const int bid = blockIdx.x;
    const int tid = threadIdx.x;

    if (bid < FUSE_BLOCKS) {
        const int split = bid & (ASPLIT - 1);
        const int chunk = (bid >> 3) & (CHUNKS - 1);
        const int i = bid >> 9;

        const int cn = ct_num[i];
        const int start = (i == 0) ? 0 : ct_num[i - 1];  // faithful: NOT cumsum

        const int qv = chunk * 256 + tid;   // vf4 index within image
        const int pix = qv << 2;
        const int y = pix >> 8;             // /W
        const int w = (pix & 255) >> 5;     // u32 word within row
        const int sh = pix & 31;

        unsigned int orw = 0u;
        for (int j = 0; j < cn; ++j) {
            const int p = min(max(start + j, 0), P_NUM - 1);  // jnp.clip
            orw |= bitws[((size_t)(p * H + y) << 3) + w];     // L1-broadcast
        }
        const vf4 mx = expand_bits(orw, sh);  // max over planes == OR of bits

        const int cbase = split * CPS;
        for (int cc = 0; cc < CPS; ++cc) {
            // plane stride in vf4 units is PIX4 = 2^14
            const size_t idx = ((size_t)(i * C_IN + cbase + cc) << 14) + qv;
            const vf4 f = reinterpret_cast<const vf4*>(feat)[idx];
            vf4 r;
            // m in {0,1} exactly -> m*f+f == f or 2f exactly, FMA-insensitive.
            r.x = fmaxf(mx.x * f.x + f.x, 0.0f);
            r.y = fmaxf(mx.y * f.y + f.y, 0.0f);
            r.z = fmaxf(mx.z * f.z + f.z, 0.0f);
            r.w = fmaxf(mx.w * f.w + f.w, 0.0f);
            __builtin_nontemporal_store(r, reinterpret_cast<vf4*>(out_cnn) + idx);
        }
    } else {
        const int b2 = bid - FUSE_BLOCKS;          // BS*C*CHUNKS blocks
        const int chunk = b2 & (CHUNKS - 1);
        const int ij = b2 >> 6;
        const int i = ij / C;
        const int j = ij - i * C;

        const int qv = chunk * 256 + tid;
        const int pix = qv << 2;
        const int y = pix >> 8;
        const int w = (pix & 255) >> 5;
        const int sh = pix & 31;

        vf4 m = {0.f, 0.f, 0.f, 0.f};
        if (j < ct_num[i]) {
            const int start = (i == 0) ? 0 : ct_num[i - 1];
            const int p = min(max(start + j, 0), P_NUM - 1);
            m = expand_bits(bitws[((size_t)(p * H + y) << 3) + w], sh);
        }
        // plane stride in vf4 units is PIX4 = 2^14
        __builtin_nontemporal_store(
            m, reinterpret_cast<vf4*>(out_mask) + ((size_t)ij << 14) + qv);
    }
}

extern "C" void kernel_launch(void* const* d_in, const int* in_sizes, int n_in,
                              void* d_out, int out_size, void* d_ws, size_t ws_size,
                              hipStream_t stream) {
    const float* contour = (const float*)d_in[0];  // [P, N, 2] f32
    const float* feat = (const float*)d_in[1];     // [BS, C_IN, H, W] f32
    const int* ct_num = (const int*)d_in[2];       // [BS] i32

    float* out = (float*)d_out;
    const int cnn_elems = BS * C_IN * PIX;
    const int C = (out_size - cnn_elems) / (BS * PIX);  // = max(ct_num)

    unsigned int* bitws = (unsigned int*)d_ws;     // [P, H, 8] u32 = 320 KB
    float* out_mask = out;
    float* out_cnn = out + (size_t)BS * C * PIX;

    hipLaunchKernelGGL(pnp_bits_kernel, dim3(P_NUM, H), dim3(256), 0, stream,
                       contour, bitws);

    const int fuse_blocks = BS * CHUNKS * ASPLIT;          // 4096
    const int expand_blocks = BS * C * CHUNKS;             // e.g. 7680 (C=15)
    hipLaunchKernelGGL(fuse_expand_kernel, dim3(fuse_blocks + expand_blocks),
                       dim3(256), 0, stream, bitws, feat, ct_num, out_mask,
                       out_cnn, C);
}